// Round 1
// baseline (63.880 us; speedup 1.0000x reference)
//
#include <hip/hip_runtime.h>
#include <hip/hip_bf16.h>

// BatchRankingLoss: G=511 groups of d=256 decoys; pairwise hinge ranking loss.
// loss = sum_{g,i,j} w_ij * max(0, 1 + y_ij*(o_i-o_j)) / (G*d*(d-1))
//   y_ij = -1 if t_i < t_j else +1;  w_ij = |t_i - t_j| > 0.1

#define DECOYS 256

__global__ __launch_bounds__(256) void brl_pair_kernel(
    const float* __restrict__ o, const float* __restrict__ t,
    float* __restrict__ partial) {
    __shared__ float so[DECOYS];
    __shared__ float st[DECOYS];
    const int g = blockIdx.x;
    const int i = threadIdx.x;
    const int base = g * DECOYS;

    const float oi = o[base + i];
    const float ti = t[base + i];
    so[i] = oi;
    st[i] = ti;
    __syncthreads();

    float acc = 0.0f;
#pragma unroll 8
    for (int j = 0; j < DECOYS; ++j) {
        const float dt = ti - st[j];
        const float y  = (dt < 0.0f) ? -1.0f : 1.0f;
        const float dd = oi - so[j];
        const float v  = fmaxf(0.0f, fmaf(y, dd, 1.0f));
        acc += (fabsf(dt) > 0.1f) ? v : 0.0f;
    }

    // wave64 shuffle reduction
#pragma unroll
    for (int off = 32; off > 0; off >>= 1)
        acc += __shfl_down(acc, off, 64);

    __shared__ float wsum[4];
    if ((i & 63) == 0) wsum[i >> 6] = acc;
    __syncthreads();
    if (i == 0)
        partial[g] = wsum[0] + wsum[1] + wsum[2] + wsum[3];
}

__global__ __launch_bounds__(256) void brl_finalize_kernel(
    const float* __restrict__ partial, float* __restrict__ out,
    int G, float invN) {
    const int i = threadIdx.x;
    float acc = 0.0f;
    for (int g = i; g < G; g += 256)
        acc += partial[g];
#pragma unroll
    for (int off = 32; off > 0; off >>= 1)
        acc += __shfl_down(acc, off, 64);

    __shared__ float wsum[4];
    if ((i & 63) == 0) wsum[i >> 6] = acc;
    __syncthreads();
    if (i == 0)
        out[0] = (wsum[0] + wsum[1] + wsum[2] + wsum[3]) * invN;
}

extern "C" void kernel_launch(void* const* d_in, const int* in_sizes, int n_in,
                              void* d_out, int out_size, void* d_ws, size_t ws_size,
                              hipStream_t stream) {
    const float* o = (const float*)d_in[0];   // input, [B,1] fp32 flat
    const float* t = (const float*)d_in[1];   // gdt_ts, [B] fp32
    float* out = (float*)d_out;

    const int B = in_sizes[1];
    const int d = DECOYS;
    const int K = B / d;
    const int G = K - 1;                      // reference skips the final group
    const float invN = 1.0f / ((float)G * (float)d * (float)(d - 1));

    float* partial = (float*)d_ws;            // G floats of scratch

    brl_pair_kernel<<<G, 256, 0, stream>>>(o, t, partial);
    brl_finalize_kernel<<<1, 256, 0, stream>>>(partial, out, G, invN);
}